// Round 5
// baseline (205.465 us; speedup 1.0000x reference)
//
#include <hip/hip_runtime.h>
#include <stdint.h>

#define MDIM 16384
#define NDIM 1020
#define KDIM 2048
#define NPAD 1024
#define TK   (KDIM / 64)   // 32 K-tiles of BK=64

typedef __attribute__((ext_vector_type(4))) float f32x4;
typedef __attribute__((ext_vector_type(8))) short short8;

#define MFMA16(a, b, c) __builtin_amdgcn_mfma_f32_16x16x32_bf16((a), (b), (c), 0, 0, 0)

// asm ds_read_b128 with register-only constraints; waits are issued manually
// (s_barrier; s_waitcnt lgkmcnt(0); sched_barrier(0)) per phase.
template <int OFF>
static __device__ __forceinline__ short8 dsr(unsigned addr) {
    short8 r;
    asm volatile("ds_read_b128 %0, %1 offset:%2" : "=v"(r) : "v"(addr), "i"(OFF));
    return r;
}

// f32 -> bf16 round-to-nearest-even
__device__ __forceinline__ unsigned short f2bf(float f) {
    unsigned int u = __float_as_uint(f);
    unsigned int r = (u + 0x7FFFu + ((u >> 16) & 1u)) >> 16;
    return (unsigned short)r;
}

// ---------------------------------------------------------------------------
// Kernel 1: W [K=2048][N=1020] f32 -> Wt [NPAD=1024][K=2048] bf16 (transposed)
// ---------------------------------------------------------------------------
__global__ void prep_w_kernel(const float* __restrict__ W,
                              unsigned short* __restrict__ Wt) {
    const int id = blockIdx.x * 256 + threadIdx.x;  // 512 blocks * 256
    const int n0 = (id & 255) * 4;
    const int k0 = (id >> 8) * 4;
    float a[4][4];
    if (n0 < NDIM) {
#pragma unroll
        for (int i = 0; i < 4; ++i) {
            const float* p = W + (size_t)(k0 + i) * NDIM + n0;
            a[i][0] = p[0]; a[i][1] = p[1]; a[i][2] = p[2]; a[i][3] = p[3];
        }
    } else {
#pragma unroll
        for (int i = 0; i < 4; ++i)
#pragma unroll
            for (int j = 0; j < 4; ++j) a[i][j] = 0.f;
    }
#pragma unroll
    for (int j = 0; j < 4; ++j) {
        uint2 p;
        p.x = (unsigned)f2bf(a[0][j]) | ((unsigned)f2bf(a[1][j]) << 16);
        p.y = (unsigned)f2bf(a[2][j]) | ((unsigned)f2bf(a[3][j]) << 16);
        *(uint2*)(Wt + (size_t)(n0 + j) * KDIM + k0) = p;
    }
}

// ---------------------------------------------------------------------------
// Kernel 1b: x [M][K] f32 -> Xb [M][K] bf16
// ---------------------------------------------------------------------------
__global__ void prep_x_kernel(const float* __restrict__ x,
                              unsigned short* __restrict__ Xb) {
    const size_t total = (size_t)MDIM * KDIM;
    const size_t stride = (size_t)gridDim.x * 256 * 8;
    for (size_t i = ((size_t)blockIdx.x * 256 + threadIdx.x) * 8; i < total; i += stride) {
        const float4 v0 = *(const float4*)(x + i);
        const float4 v1 = *(const float4*)(x + i + 4);
        uint4 p;
        p.x = (unsigned)f2bf(v0.x) | ((unsigned)f2bf(v0.y) << 16);
        p.y = (unsigned)f2bf(v0.z) | ((unsigned)f2bf(v0.w) << 16);
        p.z = (unsigned)f2bf(v1.x) | ((unsigned)f2bf(v1.y) << 16);
        p.w = (unsigned)f2bf(v1.z) | ((unsigned)f2bf(v1.w) << 16);
        *(uint4*)(Xb + i) = p;
    }
}

// ---------------------------------------------------------------------------
// Kernel 2: 256x256 GEMM, BK=64, 512 thr / 8 waves (2 wr x 4 wc), 2 phases
// per K-tile (32 MFMA each, k2-outer => 16 indep + 16 dep@dist16).
// B frags register-double-buffered (bfvP/bfvQ): tile t reads B(t+1) while
// computing with B(t). Tile-unrolled x2 so buffer indices are compile-time.
//
// Stage schedule per tile t (buf = t&1, nb = 1-buf; stripe = 64 rows):
//   phA: read A mf0..3 (buf) + B(t+1) nf0,1 (nb);
//        STAGE: A-st1,A-st3(t+1)->nb, B-st0,B-st1(t+2)->buf
//   phB: read A mf4..7 (buf) + B(t+1) nf2,3 (nb);
//        STAGE: B-st2,B-st3(t+2)->buf, A-st0,A-st2(t+2)->buf; vmcnt(2)
// FIFO invariant at tile start: all of A(t), B(t), B(t+1) landed; 2 loads
// (A-st0,A-st2 of t+1) outstanding. vmcnt(2) at phB end re-establishes it.
// WAR: every STAGE's target region was last ds_read in an EARLIER phase,
// whose lgkmcnt(0)+barrier completed those reads block-wide.
// A-stripe<->mf map: stripe = wr*2 + mf/4 (phA reads st0,2; phB st1,3).
// B-stripe s = wave wc=s's whole B band; nf0,1 = first half, nf2,3 = second.
// LDS swizzle: 16B block cb stored at (row, cb^(row&7)); 0 conflicts (R3).
// ---------------------------------------------------------------------------
extern "C" __global__ __launch_bounds__(512, 2) void gemm8_kernel(
    const unsigned short* __restrict__ Xb,
    const unsigned short* __restrict__ Wt,
    const float* __restrict__ bias,
    float* __restrict__ out) {
    extern __shared__ unsigned short lds_raw[];  // 2 bufs x (A 256x64 + B 256x64)

    const int tid  = threadIdx.x;
    const int lane = tid & 63;
    const int wid  = tid >> 6;   // 0..7
    const int wr   = wid >> 2;   // 0..1 (M)
    const int wc   = wid & 3;    // 0..3 (N)

    // XCD-aware swizzle: 256 blocks, 8 XCDs, 32 consecutive per XCD
    const int bid = blockIdx.x;
    const int swz = (bid & 7) * 32 + (bid >> 3);
    const int bm  = swz >> 2;    // 0..63
    const int bn  = swz & 3;     // 0..3

    // per-lane pre-swizzled staging source (rule 21)
    const int srow = wid * 8 + (lane >> 3);
    const int scb  = ((lane & 7) ^ (lane >> 3)) * 8;
    const unsigned short* aS = Xb + (size_t)(bm * 256 + srow) * KDIM + scb;
    const unsigned short* bS = Wt + (size_t)(bn * 256 + srow) * KDIM + scb;

#define STAGE(BUFI, OP, STRIPE, S) do {                                          \
    const size_t ks_ = (size_t)(((S) * 64) & (KDIM - 1));                        \
    const unsigned short* sp_ =                                                  \
        ((OP) ? bS : aS) + (size_t)((STRIPE) * 64) * KDIM + ks_;                 \
    __builtin_amdgcn_global_load_lds(                                            \
        (const __attribute__((address_space(1))) unsigned int*)sp_,              \
        (__attribute__((address_space(3))) unsigned int*)(lds_raw +              \
            (BUFI) * 32768 + (OP) * 16384 + ((STRIPE) * 64 + wid * 8) * 64),     \
        16, 0, 0);                                                              \
} while (0)

#define VMCNT2 do {                                                             \
    asm volatile("s_waitcnt vmcnt(2)" ::: "memory");                            \
    __builtin_amdgcn_sched_barrier(0);                                          \
} while (0)

#define PH_TAIL                                                       \
    __builtin_amdgcn_s_barrier();                                     \
    asm volatile("s_waitcnt lgkmcnt(0)" ::: "memory");                \
    __builtin_amdgcn_sched_barrier(0);                                \
    __builtin_amdgcn_s_setprio(1);

#define PH_END                                                        \
    __builtin_amdgcn_sched_barrier(0);                                \
    __builtin_amdgcn_s_setprio(0);

#define MFMA32(MB, CUR)                                                         \
    _Pragma("unroll")                                                           \
    for (int k2 = 0; k2 < 2; ++k2)                                              \
        _Pragma("unroll")                                                       \
        for (int mi = 0; mi < 4; ++mi)                                          \
            _Pragma("unroll")                                                   \
            for (int nf = 0; nf < 4; ++nf)                                      \
                acc[(MB) + mi][nf] =                                            \
                    MFMA16(af[mi][k2], CUR[nf][k2], acc[(MB) + mi][nf]);

#define TILE(T, BUF, NB, CUR, NXT)                                              \
  { /* ---- phase A ---- */                                                     \
    af[0][0]=dsr<0*2048>(aA##BUF##_0); af[0][1]=dsr<0*2048>(aA##BUF##_1);       \
    af[1][0]=dsr<1*2048>(aA##BUF##_0); af[1][1]=dsr<1*2048>(aA##BUF##_1);       \
    af[2][0]=dsr<2*2048>(aA##BUF##_0); af[2][1]=dsr<2*2048>(aA##BUF##_1);       \
    af[3][0]=dsr<3*2048>(aA##BUF##_0); af[3][1]=dsr<3*2048>(aA##BUF##_1);       \
    NXT[0][0]=dsr<0*2048>(bB##NB##_0); NXT[0][1]=dsr<0*2048>(bB##NB##_1);       \
    NXT[1][0]=dsr<1*2048>(bB##NB##_0); NXT[1][1]=dsr<1*2048>(bB##NB##_1);       \
    STAGE(NB, 0, 1, (T) + 1); STAGE(NB, 0, 3, (T) + 1);                         \
    STAGE(BUF, 1, 0, (T) + 2); STAGE(BUF, 1, 1, (T) + 2);                       \
    PH_TAIL                                                                     \
    MFMA32(0, CUR)                                                              \
    PH_END                                                                      \
    __builtin_amdgcn_s_barrier();                                               \
    /* ---- phase B ---- */                                                     \
    af[0][0]=dsr<4*2048>(aA##BUF##_0); af[0][1]=dsr<4*2048>(aA##BUF##_1);       \
    af[1][0]=dsr<5*2048>(aA##BUF##_0); af[1][1]=dsr<5*2048>(aA##BUF##_1);       \
    af[2][0]=dsr<6*2048>(aA##BUF##_0); af[2][1]=dsr<6*2048>(aA##BUF##_1);       \
    af[3][0]=dsr<7*2048>(aA##BUF##_0); af[3][1]=dsr<7*2048>(aA##BUF##_1);       \
    NXT[2][0]=dsr<2*2048>(bB##NB##_0); NXT[2][1]=dsr<2*2048>(bB##NB##_1);       \
    NXT[3][0]=dsr<3*2048>(bB##NB##_0); NXT[3][1]=dsr<3*2048>(bB##NB##_1);       \
    STAGE(BUF, 1, 2, (T) + 2); STAGE(BUF, 1, 3, (T) + 2);                       \
    STAGE(BUF, 0, 0, (T) + 2); STAGE(BUF, 0, 2, (T) + 2);                       \
    PH_TAIL                                                                     \
    MFMA32(4, CUR)                                                              \
    PH_END                                                                      \
    VMCNT2;                                                                     \
    __builtin_amdgcn_s_barrier();                                               \
  }

    // LDS read addressing: A frag(mf,k2) byte = buf*65536 + row*128 + swz(k)
    const unsigned ldsbase =
        (unsigned)(uintptr_t)(__attribute__((address_space(3))) unsigned short*)lds_raw;
    const unsigned l15 = lane & 15, hi = lane >> 4, l7 = lane & 7;
    const unsigned c0 = (unsigned)((0 * 4 + hi) ^ l7) << 4;
    const unsigned c1 = (unsigned)((1 * 4 + hi) ^ l7) << 4;
    const unsigned pbA = ldsbase + (unsigned)(wr * 128 + l15) * 128;
    const unsigned pbB = ldsbase + 32768u + (unsigned)(wc * 64 + l15) * 128;
    const unsigned aA0_0 = pbA + c0,          aA0_1 = pbA + c1;
    const unsigned aA1_0 = pbA + 65536u + c0, aA1_1 = pbA + 65536u + c1;
    const unsigned bB0_0 = pbB + c0,          bB0_1 = pbB + c1;
    const unsigned bB1_0 = pbB + 65536u + c0, bB1_1 = pbB + 65536u + c1;

    f32x4 acc[8][4];
#pragma unroll
    for (int i = 0; i < 8; ++i)
#pragma unroll
        for (int j = 0; j < 4; ++j) {
            f32x4 z = {0.f, 0.f, 0.f, 0.f};
            acc[i][j] = z;
        }

    short8 af[4][2];
    short8 bfvP[4][2], bfvQ[4][2];

    // ---- prologue: tile0 (8 stripes), B(1) (4), A-st0,A-st2(1) last ----
    STAGE(0, 0, 0, 0); STAGE(0, 0, 1, 0); STAGE(0, 0, 2, 0); STAGE(0, 0, 3, 0);
    STAGE(0, 1, 0, 0); STAGE(0, 1, 1, 0); STAGE(0, 1, 2, 0); STAGE(0, 1, 3, 0);
    STAGE(1, 1, 0, 1); STAGE(1, 1, 1, 1); STAGE(1, 1, 2, 1); STAGE(1, 1, 3, 1);
    STAGE(1, 0, 0, 1); STAGE(1, 0, 2, 1);
    VMCNT2;                       // tile0 + B(1) landed; A-st0,2(1) in flight
    __builtin_amdgcn_s_barrier();

    // preload B(0) -> bfvP (from buf0); complete block-wide before loop
    bfvP[0][0]=dsr<0*2048>(bB0_0); bfvP[0][1]=dsr<0*2048>(bB0_1);
    bfvP[1][0]=dsr<1*2048>(bB0_0); bfvP[1][1]=dsr<1*2048>(bB0_1);
    bfvP[2][0]=dsr<2*2048>(bB0_0); bfvP[2][1]=dsr<2*2048>(bB0_1);
    bfvP[3][0]=dsr<3*2048>(bB0_0); bfvP[3][1]=dsr<3*2048>(bB0_1);
    asm volatile("s_waitcnt lgkmcnt(0)" ::: "memory");
    __builtin_amdgcn_sched_barrier(0);
    __builtin_amdgcn_s_barrier();

    for (int t2 = 0; t2 < TK; t2 += 2) {
        TILE(t2,     0, 1, bfvP, bfvQ)
        TILE(t2 + 1, 1, 0, bfvQ, bfvP)
    }

    // ---- epilogue: bias + store (C/D: col=lane&15, row=(lane>>4)*4+r) ----
#pragma unroll
    for (int nf = 0; nf < 4; ++nf) {
        const int col = bn * 256 + wc * 64 + nf * 16 + (lane & 15);
        if (col < NDIM) {
            const float bv = bias[col];
#pragma unroll
            for (int mf = 0; mf < 8; ++mf) {
                const int row = bm * 256 + wr * 128 + mf * 16 + ((lane >> 4) << 2);
                float* op = out + (size_t)row * NDIM + col;
#pragma unroll
                for (int r = 0; r < 4; ++r)
                    op[(size_t)r * NDIM] = acc[mf][nf][r] + bv;
            }
        }
    }
#undef STAGE
#undef VMCNT2
#undef PH_TAIL
#undef PH_END
#undef MFMA32
#undef TILE
}

// ---------------------------------------------------------------------------
// Fallback GEMM (static 64 KiB LDS) if dynamic-LDS attr fails
// ---------------------------------------------------------------------------
__global__ void gemm_bf_kernel(const unsigned short* __restrict__ Xb,
                               const unsigned short* __restrict__ Wt,
                               const float* __restrict__ bias,
                               float* __restrict__ out) {
    __shared__ __align__(16) unsigned short As[128][32];
    __shared__ __align__(16) unsigned short Bs[128][32];

    const int tid  = threadIdx.x;
    const int lane = tid & 63;
    const int wid  = tid >> 6;
    const int wr   = wid >> 1;
    const int wc   = wid & 1;
    const int bn   = blockIdx.x;
    const int bm   = blockIdx.y;

    f32x4 acc[4][4];
#pragma unroll
    for (int i = 0; i < 4; ++i)
#pragma unroll
        for (int j = 0; j < 4; ++j) {
            f32x4 z = {0.f, 0.f, 0.f, 0.f};
            acc[i][j] = z;
        }

    const unsigned short* abase =
        Xb + (size_t)(bm * 128 + wid * 16 + (lane >> 2)) * KDIM + (lane & 3) * 8;
    const unsigned short* bbase =
        Wt + (size_t)(bn * 128 + wid * 16 + (lane >> 2)) * KDIM + (lane & 3) * 8;

    for (int kt = 0; kt < KDIM; kt += 32) {
#pragma unroll
        for (int j = 0; j < 2; ++j)
            __builtin_amdgcn_global_load_lds(
                (const __attribute__((address_space(1))) unsigned int*)(abase + (size_t)j * 64 * KDIM + kt),
                (__attribute__((address_space(3))) unsigned int*)(&As[j * 64 + wid * 16][0]),
                16, 0, 0);
#pragma unroll
        for (int j = 0; j < 2; ++j)
            __builtin_amdgcn_global_load_lds(
                (const __attribute__((address_space(1))) unsigned int*)(bbase + (size_t)j * 64 * KDIM + kt),
                (__attribute__((address_space(3))) unsigned int*)(&Bs[j * 64 + wid * 16][0]),
                16, 0, 0);
        __syncthreads();

        short8 af[4], bfr[4];
#pragma unroll
        for (int mi = 0; mi < 4; ++mi)
            af[mi] = *(const short8*)&As[wr * 64 + mi * 16 + (lane & 15)][(lane >> 4) * 8];
#pragma unroll
        for (int ni = 0; ni < 4; ++ni)
            bfr[ni] = *(const short8*)&Bs[wc * 64 + ni * 16 + (lane & 15)][(lane >> 4) * 8];

#pragma unroll
        for (int mi = 0; mi < 4; ++mi)
#pragma unroll
            for (int ni = 0; ni < 4; ++ni)
                acc[mi][ni] = MFMA16(af[mi], bfr[ni], acc[mi][ni]);

        __syncthreads();
    }

#pragma unroll
    for (int ni = 0; ni < 4; ++ni) {
        const int col = bn * 128 + wc * 64 + ni * 16 + (lane & 15);
        if (col < NDIM) {
            const float bv = bias[col];
#pragma unroll
            for (int mi = 0; mi < 4; ++mi) {
                const int row = bm * 128 + wr * 64 + mi * 16 + ((lane >> 4) << 2);
                float* op = out + (size_t)row * NDIM + col;
#pragma unroll
                for (int r = 0; r < 4; ++r)
                    op[(size_t)r * NDIM] = acc[mi][ni][r] + bv;
            }
        }
    }
}

// ---------------------------------------------------------------------------
// Kernel 3: activation. One wave per (row, span of 51 cols).
// ---------------------------------------------------------------------------
__global__ void act_kernel(const float* __restrict__ outp,
                           const float* __restrict__ u,
                           float* __restrict__ dt) {
    const int lane  = threadIdx.x & 63;
    const int gwave = (blockIdx.x * 256 + threadIdx.x) >> 6;
    const int nwave = gridDim.x * 4;
    const int total = MDIM * 20;
    const float NEG_INF = -__builtin_inff();

    for (int unit = gwave; unit < total; unit += nwave) {
        const int row = unit / 20;
        const int sp  = unit - row * 20;
        const size_t base = (size_t)row * NDIM + sp * 51;

        float o = 0.f, uu = 0.5f;
        if (lane < 51) {
            o  = outp[base + lane];
            uu = u[base + lane];
        }
        const bool soft = (lane >= 1) && (lane < 51);

        const float uc = fmaxf(uu, 1e-9f);
        const float g  = -__logf(-__logf(uc));
        float z = soft ? (o + g) * 5.0f : NEG_INF;

        float m = z;
#pragma unroll
        for (int off = 32; off; off >>= 1) m = fmaxf(m, __shfl_xor(m, off));
        float e = soft ? __expf(z - m) : 0.f;
        float s = e;
#pragma unroll
        for (int off = 32; off; off >>= 1) s += __shfl_xor(s, off);

        float res;
        if (lane == 0) {
            const float ex = __expf(-2.0f * fabsf(o));
            const float t  = (1.0f - ex) / (1.0f + ex);
            res = copysignf(t, o);
        } else {
            res = e / s;
        }
        if (lane < 51) dt[base + lane] = res;
    }
}

// ---------------------------------------------------------------------------
extern "C" void kernel_launch(void* const* d_in, const int* in_sizes, int n_in,
                              void* d_out, int out_size, void* d_ws, size_t ws_size,
                              hipStream_t stream) {
    const float* x = (const float*)d_in[0];
    const float* W = (const float*)d_in[1];
    const float* b = (const float*)d_in[2];
    const float* u = (const float*)d_in[3];
    float* out = (float*)d_out;                      // outputs [M][N]
    float* dt  = out + (size_t)MDIM * NDIM;          // data_t  [M][N]
    unsigned short* Wt = (unsigned short*)d_ws;      // bf16 [NPAD][K], 4 MiB
    unsigned short* Xb = Wt + (size_t)NPAD * KDIM;   // bf16 [M][K], 64 MiB

    prep_w_kernel<<<512, 256, 0, stream>>>(W, Wt);
    prep_x_kernel<<<2048, 256, 0, stream>>>(x, Xb);

    const hipError_t attr_ok = hipFuncSetAttribute(
        (const void*)gemm8_kernel, hipFuncAttributeMaxDynamicSharedMemorySize, 131072);
    if (attr_ok == hipSuccess) {
        gemm8_kernel<<<256, 512, 131072, stream>>>(Xb, Wt, b, out);
    } else {
        gemm_bf_kernel<<<dim3(8, 128), 256, 0, stream>>>(Xb, Wt, b, out);
    }

    act_kernel<<<8192, 256, 0, stream>>>(out, u, dt);
}

// Round 6
// 194.610 us; speedup vs baseline: 1.0558x; 1.0558x over previous
//
#include <hip/hip_runtime.h>
#include <stdint.h>

#define MDIM 16384
#define NDIM 1020
#define KDIM 2048
#define NPAD 1024
#define TK   (KDIM / 64)   // 32 K-tiles of BK=64

typedef __attribute__((ext_vector_type(4))) float f32x4;
typedef __attribute__((ext_vector_type(8))) short short8;

#define MFMA16(a, b, c) __builtin_amdgcn_mfma_f32_16x16x32_bf16((a), (b), (c), 0, 0, 0)

// asm ds_read_b128 with register-only constraints; waits issued manually via
// counted lgkmcnt (DS ops retire in order -> counted waits are exact).
template <int OFF>
static __device__ __forceinline__ short8 dsr(unsigned addr) {
    short8 r;
    asm volatile("ds_read_b128 %0, %1 offset:%2" : "=v"(r) : "v"(addr), "i"(OFF));
    return r;
}

// rule 18: every wait is followed by sched_barrier(0) so MFMAs can't hoist
// above the wait (register dataflow alone does not order them vs the asm).
#define LGKM(N)                                                       \
    asm volatile("s_waitcnt lgkmcnt(" #N ")" ::: "memory");           \
    __builtin_amdgcn_sched_barrier(0);

// f32 -> bf16 round-to-nearest-even
__device__ __forceinline__ unsigned short f2bf(float f) {
    unsigned int u = __float_as_uint(f);
    unsigned int r = (u + 0x7FFFu + ((u >> 16) & 1u)) >> 16;
    return (unsigned short)r;
}

// ---------------------------------------------------------------------------
// Kernel 1: W [K=2048][N=1020] f32 -> Wt [NPAD=1024][K=2048] bf16 (transposed)
// ---------------------------------------------------------------------------
__global__ void prep_w_kernel(const float* __restrict__ W,
                              unsigned short* __restrict__ Wt) {
    const int id = blockIdx.x * 256 + threadIdx.x;  // 512 blocks * 256
    const int n0 = (id & 255) * 4;
    const int k0 = (id >> 8) * 4;
    float a[4][4];
    if (n0 < NDIM) {
#pragma unroll
        for (int i = 0; i < 4; ++i) {
            const float* p = W + (size_t)(k0 + i) * NDIM + n0;
            a[i][0] = p[0]; a[i][1] = p[1]; a[i][2] = p[2]; a[i][3] = p[3];
        }
    } else {
#pragma unroll
        for (int i = 0; i < 4; ++i)
#pragma unroll
            for (int j = 0; j < 4; ++j) a[i][j] = 0.f;
    }
#pragma unroll
    for (int j = 0; j < 4; ++j) {
        uint2 p;
        p.x = (unsigned)f2bf(a[0][j]) | ((unsigned)f2bf(a[1][j]) << 16);
        p.y = (unsigned)f2bf(a[2][j]) | ((unsigned)f2bf(a[3][j]) << 16);
        *(uint2*)(Wt + (size_t)(n0 + j) * KDIM + k0) = p;
    }
}

// ---------------------------------------------------------------------------
// Kernel 1b: x [M][K] f32 -> Xb [M][K] bf16
// ---------------------------------------------------------------------------
__global__ void prep_x_kernel(const float* __restrict__ x,
                              unsigned short* __restrict__ Xb) {
    const size_t total = (size_t)MDIM * KDIM;
    const size_t stride = (size_t)gridDim.x * 256 * 8;
    for (size_t i = ((size_t)blockIdx.x * 256 + threadIdx.x) * 8; i < total; i += stride) {
        const float4 v0 = *(const float4*)(x + i);
        const float4 v1 = *(const float4*)(x + i + 4);
        uint4 p;
        p.x = (unsigned)f2bf(v0.x) | ((unsigned)f2bf(v0.y) << 16);
        p.y = (unsigned)f2bf(v0.z) | ((unsigned)f2bf(v0.w) << 16);
        p.z = (unsigned)f2bf(v1.x) | ((unsigned)f2bf(v1.y) << 16);
        p.w = (unsigned)f2bf(v1.z) | ((unsigned)f2bf(v1.w) << 16);
        *(uint4*)(Xb + i) = p;
    }
}

// ---------------------------------------------------------------------------
// Kernel 2: 256x256 GEMM, BK=64, 512 thr / 8 waves (2 wr x 4 wc).
// NEW STRUCTURE (R6): 2 barriers per K-tile; reads overlap MFMA via counted
// lgkmcnt. Per tile, DS issue order (indices per wave):
//   idx 0-3  : B nf0..3 @k2=0       idx 4-11 : A mf0..7 @k2=0
//   idx 12-15: B nf0..3 @k2=1       idx 16-23: A mf0..7 @k2=1 (issued mid)
// MFMA group (k2,mf) = 4 MFMAs (nf0..3); needs idx<= {k0: 4+mf, k1: 16+mf}.
// lgkm(N): N = issued_so_far - (last_needed+1); all <=15. DS retires in
// order, so each group starts exactly when its operands land; the LDS port
// streams later reads underneath the MFMA pipes.
// End of tile: barrier (reads done block-wide -> WAR-safe) -> 8 STAGEs of
// tile t+2 into buf(t) -> vmcnt(8) (ensures tile t+1 fully landed; never
// drains to 0) -> barrier.
// LDS swizzle + staging addresses byte-identical to R3/R4 (HW-verified).
// ---------------------------------------------------------------------------
extern "C" __global__ __launch_bounds__(512, 2) void gemm8_kernel(
    const unsigned short* __restrict__ Xb,
    const unsigned short* __restrict__ Wt,
    const float* __restrict__ bias,
    float* __restrict__ out) {
    extern __shared__ unsigned short lds_raw[];  // 2 bufs x (A 256x64 + B 256x64)

    const int tid  = threadIdx.x;
    const int lane = tid & 63;
    const int wid  = tid >> 6;   // 0..7
    const int wr   = wid >> 2;   // 0..1 (M)
    const int wc   = wid & 3;    // 0..3 (N)

    // XCD-aware swizzle: 256 blocks, 8 XCDs, 32 consecutive per XCD
    const int bid = blockIdx.x;
    const int swz = (bid & 7) * 32 + (bid >> 3);
    const int bm  = swz >> 2;    // 0..63
    const int bn  = swz & 3;     // 0..3

    // per-lane pre-swizzled staging source (rule 21)
    const int srow = wid * 8 + (lane >> 3);
    const int scb  = ((lane & 7) ^ (lane >> 3)) * 8;
    const unsigned short* aS = Xb + (size_t)(bm * 256 + srow) * KDIM + scb;
    const unsigned short* bS = Wt + (size_t)(bn * 256 + srow) * KDIM + scb;

#define STAGE(BUFI, OP, STRIPE, S) do {                                          \
    const size_t ks_ = (size_t)(((S) * 64) & (KDIM - 1));                        \
    const unsigned short* sp_ =                                                  \
        ((OP) ? bS : aS) + (size_t)((STRIPE) * 64) * KDIM + ks_;                 \
    __builtin_amdgcn_global_load_lds(                                            \
        (const __attribute__((address_space(1))) unsigned int*)sp_,              \
        (__attribute__((address_space(3))) unsigned int*)(lds_raw +              \
            (BUFI) * 32768 + (OP) * 16384 + ((STRIPE) * 64 + wid * 8) * 64),     \
        16, 0, 0);                                                              \
} while (0)

    // LDS read addressing (verified R3/R4): frag byte addr =
    //   A: buf*65536 + (wr*128 + mf*16 + l15)*128 + (((k2*4+hi)^l7)<<4)
    //   B: buf*65536 + 32768 + (wc*64 + nf*16 + l15)*128 + (((k2*4+hi)^l7)<<4)
    const unsigned ldsbase =
        (unsigned)(uintptr_t)(__attribute__((address_space(3))) unsigned short*)lds_raw;
    const unsigned l15 = lane & 15, hi = lane >> 4, l7 = lane & 7;
    const unsigned c0 = (unsigned)((0 * 4 + hi) ^ l7) << 4;
    const unsigned c1 = (unsigned)((1 * 4 + hi) ^ l7) << 4;
    const unsigned pbA = ldsbase + (unsigned)(wr * 128 + l15) * 128;
    const unsigned pbB = ldsbase + 32768u + (unsigned)(wc * 64 + l15) * 128;
    const unsigned aA0_0 = pbA + c0,          aA0_1 = pbA + c1;
    const unsigned aA1_0 = pbA + 65536u + c0, aA1_1 = pbA + 65536u + c1;
    const unsigned bB0_0 = pbB + c0,          bB0_1 = pbB + c1;
    const unsigned bB1_0 = pbB + 65536u + c0, bB1_1 = pbB + 65536u + c1;

    f32x4 acc[8][4];
#pragma unroll
    for (int i = 0; i < 8; ++i)
#pragma unroll
        for (int j = 0; j < 4; ++j) {
            f32x4 z = {0.f, 0.f, 0.f, 0.f};
            acc[i][j] = z;
        }

    short8 af0[8], af1[8];   // A frags @k2=0 / @k2=1
    short8 bfv[4][2];        // B frags [nf][k2]

#define RB(BUF, K)                                                    \
    bfv[0][K] = dsr<0 * 2048>(bB##BUF##_##K);                         \
    bfv[1][K] = dsr<1 * 2048>(bB##BUF##_##K);                         \
    bfv[2][K] = dsr<2 * 2048>(bB##BUF##_##K);                         \
    bfv[3][K] = dsr<3 * 2048>(bB##BUF##_##K);

#define RA(BUF, K, MF) af##K[MF] = dsr<(MF) * 2048>(aA##BUF##_##K);

#define G(K, MF, LG)                                                  \
    LGKM(LG)                                                          \
    __builtin_amdgcn_s_setprio(1);                                    \
    acc[MF][0] = MFMA16(af##K[MF], bfv[0][K], acc[MF][0]);            \
    acc[MF][1] = MFMA16(af##K[MF], bfv[1][K], acc[MF][1]);            \
    acc[MF][2] = MFMA16(af##K[MF], bfv[2][K], acc[MF][2]);            \
    acc[MF][3] = MFMA16(af##K[MF], bfv[3][K], acc[MF][3]);            \
    __builtin_amdgcn_s_setprio(0);

#define TILE(T, BUF)                                                            \
  {                                                                             \
    RB(BUF, 0)                                       /* idx 0-3   */           \
    RA(BUF, 0, 0) RA(BUF, 0, 1) RA(BUF, 0, 2) RA(BUF, 0, 3)                     \
    RA(BUF, 0, 4) RA(BUF, 0, 5) RA(BUF, 0, 6) RA(BUF, 0, 7) /* idx 4-11 */      \
    RB(BUF, 1)                                       /* idx 12-15 */           \
    G(0, 0, 11) G(0, 1, 10) G(0, 2, 9) G(0, 3, 8) G(0, 4, 7) G(0, 5, 6)         \
    RA(BUF, 1, 0) RA(BUF, 1, 1) RA(BUF, 1, 2) RA(BUF, 1, 3)                     \
    RA(BUF, 1, 4) RA(BUF, 1, 5) RA(BUF, 1, 6) RA(BUF, 1, 7) /* idx 16-23 */     \
    G(0, 6, 13) G(0, 7, 12)                                                     \
    G(1, 0, 7) G(1, 1, 6) G(1, 2, 5) G(1, 3, 4)                                 \
    G(1, 4, 3) G(1, 5, 2) G(1, 6, 1) G(1, 7, 0)                                 \
    __builtin_amdgcn_s_barrier();  /* all waves' reads done -> WAR-safe */      \
    STAGE(BUF, 0, 0, (T) + 2); STAGE(BUF, 0, 1, (T) + 2);                       \
    STAGE(BUF, 0, 2, (T) + 2); STAGE(BUF, 0, 3, (T) + 2);                       \
    STAGE(BUF, 1, 0, (T) + 2); STAGE(BUF, 1, 1, (T) + 2);                       \
    STAGE(BUF, 1, 2, (T) + 2); STAGE(BUF, 1, 3, (T) + 2);                       \
    asm volatile("s_waitcnt vmcnt(8)" ::: "memory"); /* t+1 fully landed */     \
    __builtin_amdgcn_sched_barrier(0);                                          \
    __builtin_amdgcn_s_barrier();                                               \
  }

    // ---- prologue: stage tile0 -> buf0, tile1 -> buf1; wait tile0 ----
    STAGE(0, 0, 0, 0); STAGE(0, 0, 1, 0); STAGE(0, 0, 2, 0); STAGE(0, 0, 3, 0);
    STAGE(0, 1, 0, 0); STAGE(0, 1, 1, 0); STAGE(0, 1, 2, 0); STAGE(0, 1, 3, 0);
    STAGE(1, 0, 0, 1); STAGE(1, 0, 1, 1); STAGE(1, 0, 2, 1); STAGE(1, 0, 3, 1);
    STAGE(1, 1, 0, 1); STAGE(1, 1, 1, 1); STAGE(1, 1, 2, 1); STAGE(1, 1, 3, 1);
    asm volatile("s_waitcnt vmcnt(8)" ::: "memory");  // tile0 landed
    __builtin_amdgcn_sched_barrier(0);
    __builtin_amdgcn_s_barrier();

    for (int t2 = 0; t2 < TK; t2 += 2) {
        TILE(t2, 0)
        TILE(t2 + 1, 1)
    }

    // ---- epilogue: bias + store (C/D: col=lane&15, row=(lane>>4)*4+r) ----
#pragma unroll
    for (int nf = 0; nf < 4; ++nf) {
        const int col = bn * 256 + wc * 64 + nf * 16 + (lane & 15);
        if (col < NDIM) {
            const float bv = bias[col];
#pragma unroll
            for (int mf = 0; mf < 8; ++mf) {
                const int row = bm * 256 + wr * 128 + mf * 16 + ((lane >> 4) << 2);
                float* op = out + (size_t)row * NDIM + col;
#pragma unroll
                for (int r = 0; r < 4; ++r)
                    op[(size_t)r * NDIM] = acc[mf][nf][r] + bv;
            }
        }
    }
#undef STAGE
#undef RB
#undef RA
#undef G
#undef TILE
}

// ---------------------------------------------------------------------------
// Fallback GEMM (static 64 KiB LDS) if dynamic-LDS attr fails
// ---------------------------------------------------------------------------
__global__ void gemm_bf_kernel(const unsigned short* __restrict__ Xb,
                               const unsigned short* __restrict__ Wt,
                               const float* __restrict__ bias,
                               float* __restrict__ out) {
    __shared__ __align__(16) unsigned short As[128][32];
    __shared__ __align__(16) unsigned short Bs[128][32];

    const int tid  = threadIdx.x;
    const int lane = tid & 63;
    const int wid  = tid >> 6;
    const int wr   = wid >> 1;
    const int wc   = wid & 1;
    const int bn   = blockIdx.x;
    const int bm   = blockIdx.y;

    f32x4 acc[4][4];
#pragma unroll
    for (int i = 0; i < 4; ++i)
#pragma unroll
        for (int j = 0; j < 4; ++j) {
            f32x4 z = {0.f, 0.f, 0.f, 0.f};
            acc[i][j] = z;
        }

    const unsigned short* abase =
        Xb + (size_t)(bm * 128 + wid * 16 + (lane >> 2)) * KDIM + (lane & 3) * 8;
    const unsigned short* bbase =
        Wt + (size_t)(bn * 128 + wid * 16 + (lane >> 2)) * KDIM + (lane & 3) * 8;

    for (int kt = 0; kt < KDIM; kt += 32) {
#pragma unroll
        for (int j = 0; j < 2; ++j)
            __builtin_amdgcn_global_load_lds(
                (const __attribute__((address_space(1))) unsigned int*)(abase + (size_t)j * 64 * KDIM + kt),
                (__attribute__((address_space(3))) unsigned int*)(&As[j * 64 + wid * 16][0]),
                16, 0, 0);
#pragma unroll
        for (int j = 0; j < 2; ++j)
            __builtin_amdgcn_global_load_lds(
                (const __attribute__((address_space(1))) unsigned int*)(bbase + (size_t)j * 64 * KDIM + kt),
                (__attribute__((address_space(3))) unsigned int*)(&Bs[j * 64 + wid * 16][0]),
                16, 0, 0);
        __syncthreads();

        short8 af[4], bfr[4];
#pragma unroll
        for (int mi = 0; mi < 4; ++mi)
            af[mi] = *(const short8*)&As[wr * 64 + mi * 16 + (lane & 15)][(lane >> 4) * 8];
#pragma unroll
        for (int ni = 0; ni < 4; ++ni)
            bfr[ni] = *(const short8*)&Bs[wc * 64 + ni * 16 + (lane & 15)][(lane >> 4) * 8];

#pragma unroll
        for (int mi = 0; mi < 4; ++mi)
#pragma unroll
            for (int ni = 0; ni < 4; ++ni)
                acc[mi][ni] = MFMA16(af[mi], bfr[ni], acc[mi][ni]);

        __syncthreads();
    }

#pragma unroll
    for (int ni = 0; ni < 4; ++ni) {
        const int col = bn * 128 + wc * 64 + ni * 16 + (lane & 15);
        if (col < NDIM) {
            const float bv = bias[col];
#pragma unroll
            for (int mi = 0; mi < 4; ++mi) {
                const int row = bm * 128 + wr * 64 + mi * 16 + ((lane >> 4) << 2);
                float* op = out + (size_t)row * NDIM + col;
#pragma unroll
                for (int r = 0; r < 4; ++r)
                    op[(size_t)r * NDIM] = acc[mi][ni][r] + bv;
            }
        }
    }
}

// ---------------------------------------------------------------------------
// Kernel 3: activation. One wave per (row, span of 51 cols).
// ---------------------------------------------------------------------------
__global__ void act_kernel(const float* __restrict__ outp,
                           const float* __restrict__ u,
                           float* __restrict__ dt) {
    const int lane  = threadIdx.x & 63;
    const int gwave = (blockIdx.x * 256 + threadIdx.x) >> 6;
    const int nwave = gridDim.x * 4;
    const int total = MDIM * 20;
    const float NEG_INF = -__builtin_inff();

    for (int unit = gwave; unit < total; unit += nwave) {
        const int row = unit / 20;
        const int sp  = unit - row * 20;
        const size_t base = (size_t)row * NDIM + sp * 51;

        float o = 0.f, uu = 0.5f;
        if (lane < 51) {
            o  = outp[base + lane];
            uu = u[base + lane];
        }
        const bool soft = (lane >= 1) && (lane < 51);

        const float uc = fmaxf(uu, 1e-9f);
        const float g  = -__logf(-__logf(uc));
        float z = soft ? (o + g) * 5.0f : NEG_INF;

        float m = z;
#pragma unroll
        for (int off = 32; off; off >>= 1) m = fmaxf(m, __shfl_xor(m, off));
        float e = soft ? __expf(z - m) : 0.f;
        float s = e;
#pragma unroll
        for (int off = 32; off; off >>= 1) s += __shfl_xor(s, off);

        float res;
        if (lane == 0) {
            const float ex = __expf(-2.0f * fabsf(o));
            const float t  = (1.0f - ex) / (1.0f + ex);
            res = copysignf(t, o);
        } else {
            res = e / s;
        }
        if (lane < 51) dt[base + lane] = res;
    }
}

// ---------------------------------------------------------------------------
extern "C" void kernel_launch(void* const* d_in, const int* in_sizes, int n_in,
                              void* d_out, int out_size, void* d_ws, size_t ws_size,
                              hipStream_t stream) {
    const float* x = (const float*)d_in[0];
    const float* W = (const float*)d_in[1];
    const float* b = (const float*)d_in[2];
    const float* u = (const float*)d_in[3];
    float* out = (float*)d_out;                      // outputs [M][N]
    float* dt  = out + (size_t)MDIM * NDIM;          // data_t  [M][N]
    unsigned short* Wt = (unsigned short*)d_ws;      // bf16 [NPAD][K], 4 MiB
    unsigned short* Xb = Wt + (size_t)NPAD * KDIM;   // bf16 [M][K], 64 MiB

    prep_w_kernel<<<512, 256, 0, stream>>>(W, Wt);
    prep_x_kernel<<<2048, 256, 0, stream>>>(x, Xb);

    const hipError_t attr_ok = hipFuncSetAttribute(
        (const void*)gemm8_kernel, hipFuncAttributeMaxDynamicSharedMemorySize, 131072);
    if (attr_ok == hipSuccess) {
        gemm8_kernel<<<256, 512, 131072, stream>>>(Xb, Wt, b, out);
    } else {
        gemm_bf_kernel<<<dim3(8, 128), 256, 0, stream>>>(Xb, Wt, b, out);
    }

    act_kernel<<<8192, 256, 0, stream>>>(out, u, dt);
}